// Round 6
// baseline (110.338 us; speedup 1.0000x reference)
//
#include <hip/hip_runtime.h>
#include <math.h>

#define L2PI 1.8378770664093454835606594728112
#define LN2  0.69314718055994530941723212145818
#define MAGIC 0x7E57C0DE

// ---------------------------------------------------------------------------
// Lane-parallel Gaussian potential over (F = first state(4), L = last state(4),
// B = class-bias means(4)).  16 lanes per potential; lane (i,j) = ((l>>2)&3, l&3)
// holds element (i,j) of each 4x4 J block; h vectors replicated over rows
// (lane (i,j) holds h[j]); g/dm/de replicated.  log psi = g + h.x - 0.5 x'Jx,
// with running det product in (dm, de):  effective g -= 0.5*(log dm + de*ln2).
// ---------------------------------------------------------------------------
struct LP {
    double jFF, jFL, jFB, jLL, jLB, jBB;
    double hF, hL, hB, g, dm, de;
};

struct Cn { double qa, qb, qc, wa, wb, ri, Cstep; };

__device__ __forceinline__ double shf(double v, int s) { return __shfl(v, s, 64); }
__device__ __forceinline__ double sx (double v, int m) { return __shfl_xor(v, m, 64); }

// Single-step potential: N(z'; F z, Qs) * prod_k N(y_k; b_k + z'_{h_k}, r)
__device__ __forceinline__ LP init_lane(double x0, double x1, const Cn& C, int i, int j) {
    LP P;
    double v = 0.0;
    if (i == j) v = (i < 2) ? C.qa : C.qc;
    if ((i ^ j) == 2) v = C.wa;
    P.jFF = v;
    v = 0.0;
    if (j == (i & 1))     v = (i < 2) ? -C.qa : -C.wa;
    if (j == (i & 1) + 2) v = (i < 2) ? -C.qb : -C.wb;
    P.jFL = v;
    P.jFB = 0.0;
    v = 0.0;
    if (i == j) v = ((i < 2) ? C.qa : C.qc) + (((i & 1) == 0) ? 2.0*C.ri : 0.0);
    if ((i ^ j) == 2) v = C.qb;
    P.jLL = v;
    P.jLB = (((i == 0) && (j < 2)) || ((i == 2) && (j >= 2))) ? C.ri : 0.0;
    P.jBB = (i == j) ? C.ri : 0.0;
    P.hF = 0.0;
    P.hL = ((j & 1) == 0) ? C.ri * (x0 + x1) : 0.0;
    P.hB = C.ri * ((j & 1) ? x1 : x0);
    P.g  = -C.ri * (x0*x0 + x1*x1) + C.Cstep;
    P.dm = 1.0; P.de = 0.0;
    return P;
}

// Compose P1 (earlier) o P2 (later), marginalizing the shared middle state.
__device__ __forceinline__ LP compose(const LP& P1, const LP& P2, int gb, int i, int j) {
    double hm = P1.hL + P2.hF;
    double Mb = P1.jLB + P2.jFB;
    double S  = P1.jLL + P2.jFF;
    double dm = P1.dm * P2.dm;
    double de = P1.de + P2.de;
    { int ex; dm = frexp(dm, &ex); de += (double)ex; }
    // GJ inverse of SPD S (pivots positive); det folded into dm/de
    double K = (i == j) ? 1.0 : 0.0;
    #pragma unroll
    for (int p = 0; p < 4; ++p) {
        double piv = shf(S, gb + 5*p);
        dm *= piv;
        double ip  = 1.0 / piv;
        double Apj = shf(S, gb + 4*p + j) * ip;
        double Kpj = shf(K, gb + 4*p + j) * ip;
        double f   = shf(S, gb + 4*i + p);
        bool isp = (i == p);
        S = isp ? S * ip : fma(-f, Apj, S);
        K = isp ? K * ip : fma(-f, Kpj, K);
    }
    { int ex; dm = frexp(dm, &ex); de += (double)ex; }
    const double Si = K;
    double sr[4], sc[4], f1r[4], f1T[4], f2c[4], f2T[4], mc[4], mT[4], hmc[4];
    #pragma unroll
    for (int r = 0; r < 4; ++r) {
        sr[r]  = shf(Si, gb + 4*i + r);
        sc[r]  = shf(Si, gb + 4*r + j);
        f1r[r] = shf(P1.jFL, gb + 4*i + r);
        f1T[r] = shf(P1.jFL, gb + 4*j + r);
        f2c[r] = shf(P2.jFL, gb + 4*r + j);
        f2T[r] = shf(P2.jFL, gb + 4*r + i);
        mc[r]  = shf(Mb, gb + 4*r + j);
        mT[r]  = shf(Mb, gb + 4*r + i);
        hmc[r] = shf(hm, gb + 5*r);
    }
    double A1 = 0.0, C1 = 0.0, B2 = 0.0, v4i = 0.0;
    #pragma unroll
    for (int r = 0; r < 4; ++r) {
        A1  = fma(f1r[r], sc[r], A1);
        C1  = fma(sr[r], mc[r], C1);
        B2  = fma(sr[r], f2c[r], B2);
        v4i = fma(sr[r], hmc[r], v4i);
    }
    double a1r[4], c1c[4], b2c[4], v4c[4];
    #pragma unroll
    for (int r = 0; r < 4; ++r) {
        a1r[r] = shf(A1, gb + 4*i + r);
        c1c[r] = shf(C1, gb + 4*r + j);
        b2c[r] = shf(B2, gb + 4*r + j);
        v4c[r] = shf(v4i, gb + 5*r);
    }
    double s_ff=0, s_fl=0, s_fb=0, s_ll=0, s_lb=0, s_bb=0, s_hf=0, s_hl=0, s_hb=0, s_g=0;
    #pragma unroll
    for (int r = 0; r < 4; ++r) {
        s_ff = fma(a1r[r], f1T[r], s_ff);
        s_fl = fma(a1r[r], f2c[r], s_fl);
        s_fb = fma(a1r[r], mc[r],  s_fb);
        s_ll = fma(f2T[r], b2c[r], s_ll);
        s_lb = fma(f2T[r], c1c[r], s_lb);
        s_bb = fma(mT[r],  c1c[r], s_bb);
        s_hf = fma(a1r[r], hmc[r], s_hf);
        s_hl = fma(f2c[r], v4c[r], s_hl);
        s_hb = fma(mc[r],  v4c[r], s_hb);
        s_g  = fma(hmc[r], v4c[r], s_g);
    }
    LP R;
    R.jFF = P1.jFF - s_ff;
    R.jFL = -s_fl;
    R.jFB = P1.jFB - s_fb;
    R.jLL = P2.jLL - s_ll;
    R.jLB = P2.jLB - s_lb;
    R.jBB = P1.jBB + P2.jBB - s_bb;
    R.hF  = P1.hF - shf(s_hf, gb + 5*j);
    R.hL  = P2.hL - s_hl;
    R.hB  = P1.hB + P2.hB - s_hb;
    R.g   = P1.g + P2.g + 2.0*L2PI + 0.5*s_g;
    R.dm = dm; R.de = de;
    return R;
}

__device__ __forceinline__ LP fetchx(const LP& P, int m) {
    LP O;
    O.jFF = sx(P.jFF,m); O.jFL = sx(P.jFL,m); O.jFB = sx(P.jFB,m);
    O.jLL = sx(P.jLL,m); O.jLB = sx(P.jLB,m); O.jBB = sx(P.jBB,m);
    O.hF  = sx(P.hF,m);  O.hL  = sx(P.hL,m);  O.hB  = sx(P.hB,m);
    O.g   = sx(P.g,m);   O.dm  = sx(P.dm,m);  O.de  = sx(P.de,m);
    return O;
}
__device__ __forceinline__ LP csel(bool up, const LP& O, const LP& P) {
    LP A;
    A.jFF = up?O.jFF:P.jFF; A.jFL = up?O.jFL:P.jFL; A.jFB = up?O.jFB:P.jFB;
    A.jLL = up?O.jLL:P.jLL; A.jLB = up?O.jLB:P.jLB; A.jBB = up?O.jBB:P.jBB;
    A.hF  = up?O.hF :P.hF;  A.hL  = up?O.hL :P.hL;  A.hB  = up?O.hB :P.hB;
    A.g   = up?O.g  :P.g;   A.dm  = up?O.dm :P.dm;  A.de  = up?O.de :P.de;
    return A;
}
__device__ __forceinline__ void pot_store(double* p, const LP& P) {
    p[0]=P.jFF; p[1]=P.jFL; p[2]=P.jFB; p[3]=P.jLL; p[4]=P.jLB; p[5]=P.jBB;
    p[6]=P.hF;  p[7]=P.hL;  p[8]=P.hB;  p[9]=P.g;   p[10]=P.dm; p[11]=P.de;
}
__device__ __forceinline__ LP pot_load(const double* p) {
    LP P;
    P.jFF=p[0]; P.jFL=p[1]; P.jFB=p[2]; P.jLL=p[3]; P.jLB=p[4]; P.jBB=p[5];
    P.hF=p[6];  P.hL=p[7];  P.hB=p[8];  P.g=p[9];   P.dm=p[10]; P.de=p[11];
    return P;
}
// coherent (device-scope) pot load — bypasses possibly-stale caches
__device__ __forceinline__ double cload(const double* p) {
    return __hip_atomic_load(p, __ATOMIC_RELAXED, __HIP_MEMORY_SCOPE_AGENT);
}
__device__ __forceinline__ LP pot_load_coh(const double* p) {
    LP P;
    P.jFF=cload(p+0); P.jFL=cload(p+1); P.jFB=cload(p+2);
    P.jLL=cload(p+3); P.jLB=cload(p+4); P.jBB=cload(p+5);
    P.hF=cload(p+6);  P.hL=cload(p+7);  P.hB=cload(p+8);
    P.g=cload(p+9);   P.dm=cload(p+10); P.de=cload(p+11);
    return P;
}

__device__ __forceinline__ Cn make_cn(double sg2, double qn2) {
    Cn C;
    C.qa = 12.0/qn2; C.qb = -6.0/qn2; C.qc = 4.0/qn2;
    C.wa = 6.0/qn2;  C.wb = -2.0/qn2;
    C.ri = 32.0/sg2;
    const double r = sg2/32.0;
    C.Cstep = -2.0*log(2.0*M_PI*r) - 2.0*L2PI - 0.5*(4.0*log(qn2) - 2.0*log(12.0));
    return C;
}

// ---------- Fused kernel: 32 blocks x 256 threads.
// Produce: each block folds 64 steps -> 1 chunk pot -> ws + release flag.
// Consume (block 0 only): spin on 32 flags, fold 32 pots (waves 0-1),
// finalize (wave 0), expand (all 256). ----------
__global__ __launch_bounds__(256)
void hmm_fused(const float* __restrict__ track,
               const float* __restrict__ bias_scales,
               const float* __restrict__ obs_noise_p,
               const float* __restrict__ trans_noise_p,
               double* __restrict__ ws,
               float* __restrict__ out)
{
    __shared__ double pool[2][4][16][13];
    __shared__ double sTi[8][8];
    __shared__ double sA[4];
    __shared__ double sLL;
    const int tid = (int)threadIdx.x;
    const int l = tid & 63, w = tid >> 6;
    const int i = (l >> 2) & 3, j = l & 3, gb = l & 48, g = (l >> 4) & 3;
    const int bid = (int)blockIdx.x;

    const double sg2 = (double)obs_noise_p[0] * (double)obs_noise_p[0];
    const double qn2 = (double)trans_noise_p[0] * (double)trans_noise_p[0];
    const double a00 = (double)bias_scales[0];
    const double a01 = (double)bias_scales[1];
    const Cn C = make_cn(sg2, qn2);

    int* flags = (int*)(ws + 32*16*12);   // after 48 KB of pots; 128 B stride

    // ================= produce phase (all 32 blocks) =================
    {
        const int G = bid * 16 + w * 4 + g;   // group 0..511, 4 steps
        const int t0 = G * 4;
        LP P = init_lane((double)track[2*t0+0], (double)track[2*t0+1], C, i, j);
        #pragma unroll 1
        for (int op = 0; op < 7; ++op) {
            LP A, Bp;
            if (op < 3) {
                const int t = t0 + op + 1;
                A  = P;
                Bp = init_lane((double)track[2*t+0], (double)track[2*t+1], C, i, j);
            } else if (op < 5) {
                const int m = 16 << (op - 3);
                LP O = fetchx(P, m);
                const bool up = (l & m) != 0;
                A  = csel(up, O, P);
                Bp = csel(up, P, O);
            } else {
                const int s = 1 << (op - 5);
                const int buf = op - 5;
                if (l < 16) pot_store(&pool[buf][w][l][0], P);
                __syncthreads();
                LP O = pot_load(&pool[buf][w ^ s][l & 15][0]);
                const bool up = (w & s) != 0;
                A  = csel(up, O, P);
                Bp = csel(up, P, O);
            }
            P = compose(A, Bp, gb, i, j);
        }
        if (w == 0 && l < 16)
            pot_store(ws + ((size_t)bid * 16 + l) * 12, P);
        __threadfence();
        __syncthreads();
        if (tid == 0)
            __hip_atomic_store(&flags[bid * 32], MAGIC,
                               __ATOMIC_RELEASE, __HIP_MEMORY_SCOPE_AGENT);
    }
    if (bid != 0) return;

    // ================= consume phase (block 0) =================
    if (tid < 32) {
        while (__hip_atomic_load(&flags[tid * 32],
                                 __ATOMIC_ACQUIRE, __HIP_MEMORY_SCOPE_AGENT) != MAGIC)
            __builtin_amdgcn_s_sleep(2);
    }
    __syncthreads();
    __threadfence();

    const bool act = (w < 2);
    LP P;
    if (act) {
        const int G = w * 4 + g;                              // group 0..7
        const size_t base = ((size_t)G * 4 * 16 + (size_t)(l & 15)) * 12;
        P = pot_load_coh(ws + base);
        #pragma unroll 1
        for (int op = 0; op < 6; ++op) {
            LP A, Bp;
            if (op < 3) {
                A  = P;
                Bp = pot_load_coh(ws + base + (size_t)(op + 1) * 16 * 12);
            } else if (op < 5) {
                const int m = 16 << (op - 3);
                LP O = fetchx(P, m);
                const bool up = (l & m) != 0;
                A  = csel(up, O, P);
                Bp = csel(up, P, O);
            } else {
                if (l < 16) pot_store(&pool[0][w][l][0], P);
                __syncthreads();
                LP O = pot_load(&pool[0][w ^ 1][l & 15][0]);
                const bool up = (w & 1) != 0;
                A  = csel(up, O, P);
                Bp = csel(up, P, O);
            }
            P = compose(A, Bp, gb, i, j);
        }
    } else {
        __syncthreads();   // match op==5 barrier
    }

    // ---------- final stage on wave 0 ----------
    if (w == 0) {
        const double a0i = (i & 1) ? a01 : a00;
        P.jFF += (i == j) ? 1.0 : 0.0;
        P.jBB += (i == j) ? 32.0 / a0i : 0.0;
        P.g   += -4.0*L2PI + 2.0*log(32.0) - log(a00) - log(a01);
        double dm = P.dm, de = P.de;
        // marginalize z0: GJ inverse of jFF
        double K = (i == j) ? 1.0 : 0.0;
        double S = P.jFF;
        #pragma unroll
        for (int p = 0; p < 4; ++p) {
            double piv = shf(S, gb + 5*p);
            dm *= piv;
            double ip  = 1.0 / piv;
            double Apj = shf(S, gb + 4*p + j) * ip;
            double Kpj = shf(K, gb + 4*p + j) * ip;
            double f   = shf(S, gb + 4*i + p);
            bool isp = (i == p);
            S = isp ? S * ip : fma(-f, Apj, S);
            K = isp ? K * ip : fma(-f, Kpj, K);
        }
        { int ex; dm = frexp(dm, &ex); de += (double)ex; }
        const double Si = K;
        double sr[4], fr[4], fT[4], bc[4], bT[4], hfc[4];
        #pragma unroll
        for (int r = 0; r < 4; ++r) {
            sr[r]  = shf(Si, gb + 4*i + r);
            fr[r]  = shf(P.jFL, gb + 4*r + i);
            fT[r]  = shf(P.jFL, gb + 4*r + j);
            bc[r]  = shf(P.jFB, gb + 4*r + i);
            bT[r]  = shf(P.jFB, gb + 4*r + j);
            hfc[r] = shf(P.hF, gb + 5*r);
        }
        double YL = 0.0, YB = 0.0, yFi = 0.0;
        #pragma unroll
        for (int r = 0; r < 4; ++r) {
            YL  = fma(sr[r], fT[r], YL);
            YB  = fma(sr[r], bT[r], YB);
            yFi = fma(sr[r], hfc[r], yFi);
        }
        double ylc[4], ybc[4], yfc[4];
        #pragma unroll
        for (int r = 0; r < 4; ++r) {
            ylc[r] = shf(YL, gb + 4*r + j);
            ybc[r] = shf(YB, gb + 4*r + j);
            yfc[r] = shf(yFi, gb + 5*r);
        }
        double s1 = 0.0, s2 = 0.0, s3 = 0.0, sh1 = 0.0, sh2 = 0.0, qF = 0.0;
        #pragma unroll
        for (int r = 0; r < 4; ++r) {
            s1  = fma(fr[r], ylc[r], s1);
            s2  = fma(fr[r], ybc[r], s2);
            s3  = fma(bc[r], ybc[r], s3);
            sh1 = fma(fT[r], yfc[r], sh1);
            sh2 = fma(bT[r], yfc[r], sh2);
            qF  = fma(hfc[r], yfc[r], qF);
        }
        double J8ss = P.jLL - s1;
        double J8sb = P.jLB - s2;
        double J8bb = P.jBB - s3;
        double h8s  = P.hL - sh1;
        double h8b  = P.hB - sh2;
        double g8   = P.g + 2.0*L2PI + 0.5*qF;

        // 8x8 stage across all 64 lanes: lane = (I,J)
        const int I = l >> 3, J = l & 7, i4 = I & 3, j4 = J & 3;
        double ss  = shf(J8ss, 4*i4 + j4);
        double sb  = shf(J8sb, 4*i4 + j4);
        double sbT = shf(J8sb, 4*j4 + i4);
        double bb  = shf(J8bb, 4*i4 + j4);
        double A8 = (I < 4) ? ((J < 4) ? ss : sb) : ((J < 4) ? sbT : bb);
        const double J8sav = A8;
        double h8v = (J < 4) ? shf(h8s, j4) : shf(h8b, j4);
        double h8r = (I < 4) ? shf(h8s, i4) : shf(h8b, i4);
        double K8 = (I == J) ? 1.0 : 0.0;
        #pragma unroll 1
        for (int p = 0; p < 8; ++p) {
            double piv = shf(A8, 9*p);
            dm *= piv; { int ex; dm = frexp(dm, &ex); de += (double)ex; }
            double ip = 1.0 / piv;
            double Ap = shf(A8, 8*p + J) * ip;
            double Kp = shf(K8, 8*p + J) * ip;
            double f  = shf(A8, 8*I + p);
            bool isp = (I == p);
            A8 = isp ? A8 * ip : fma(-f, Ap, A8);
            K8 = isp ? K8 * ip : fma(-f, Kp, K8);
        }
        double tq = h8r * K8 * h8v;
        tq += sx(tq,1); tq += sx(tq,2); tq += sx(tq,4);
        tq += sx(tq,8); tq += sx(tq,16); tq += sx(tq,32);

        double ll = g8 + 4.0*L2PI - 0.5*(log(dm) + de*LN2) + 0.5*tq;
        const double Td = 2048.0;
        const double c0 = sg2/a00, c1 = sg2/a01;
        ll += -31.0*(Td*(L2PI + log(sg2)) + log((c0+Td)/c0))
              -31.0*(Td*(L2PI + log(sg2)) + log((c1+Td)/c1))
              -2.0*Td*log(32.0);

        const double i32 = 1.0/32.0, irn = 0.17677669529663688110021109052621;
        int a = (I >= 4) ? I - 4 : I + 4;
        int b = (J >= 4) ? J - 4 : J + 4;
        double scale = (I >= 4 && J >= 4) ? i32 : (((I >= 4) != (J >= 4)) ? irn : 1.0);
        sTi[a][b] = J8sav * scale;
        if (l < 4) { double a0k = (l & 1) ? a01 : a00; sA[l] = a0k*sg2/(sg2 + Td*a0k); }
        if (l == 0) sLL = ll;
    }
    __syncthreads();

    // ---------- expand 1 + 132x132 outputs ----------
    const double inv32 = 1.0/32.0;
    const double invrn = 0.17677669529663688110021109052621;
    const int total = 1 + 132*132;
    #pragma unroll 1
    for (int idx = tid; idx < total; idx += 256) {
        double v;
        if (idx == 0) {
            v = sLL;
        } else {
            int el = idx - 1;
            int r = el / 132;
            int cc = el - 132*r;
            if (r < 128) {
                int ki = ((r >> 6) << 1) | (r & 1);
                if (cc < 128) {
                    int kj = ((cc >> 6) << 1) | (cc & 1);
                    v = sTi[ki][kj] * inv32;
                    if (ki == kj) {
                        double ia = 1.0 / sA[ki];
                        v -= ia * inv32;
                        if (r == cc) v += ia;
                    }
                } else {
                    v = sTi[ki][cc - 124] * invrn;
                }
            } else {
                if (cc < 128) {
                    int kj = ((cc >> 6) << 1) | (cc & 1);
                    v = sTi[kj][r - 124] * invrn;
                } else {
                    v = sTi[r - 124][cc - 124];
                }
            }
        }
        out[idx] = (float)v;
    }
}

extern "C" void kernel_launch(void* const* d_in, const int* in_sizes, int n_in,
                              void* d_out, int out_size, void* d_ws, size_t ws_size,
                              hipStream_t stream) {
    (void)in_sizes; (void)n_in; (void)out_size; (void)ws_size;
    const float* track       = (const float*)d_in[0];
    const float* bias_scales = (const float*)d_in[1];
    const float* obs_noise   = (const float*)d_in[2];
    const float* trans_noise = (const float*)d_in[3];
    float* out = (float*)d_out;
    double* ws = (double*)d_ws;   // 48 KB pots + flags (poisoned 0xAA != MAGIC each replay)
    hipLaunchKernelGGL(hmm_fused, dim3(32), dim3(256), 0, stream,
                       track, bias_scales, obs_noise, trans_noise, ws, out);
}

// Round 7
// 97.283 us; speedup vs baseline: 1.1342x; 1.1342x over previous
//
#include <hip/hip_runtime.h>
#include <math.h>

#define L2PI 1.8378770664093454835606594728112
#define LN2  0.69314718055994530941723212145818
#define MAGIC 0x7E57C0DE

// ---------------------------------------------------------------------------
// Lane-parallel Gaussian potential (fp32) over (F = first state(4),
// L = last state(4), B = class-bias means(4)).  16 lanes per potential;
// lane (i,j) holds element (i,j) of each 4x4 J block; h vectors replicated
// over rows (lane (i,j) holds h[j]); g/dm/de replicated.
// log psi = g + h.x - 0.5 x'Jx, det product carried in (dm, de).
// ---------------------------------------------------------------------------
struct LP {
    float jFF, jFL, jFB, jLL, jLB, jBB;
    float hF, hL, hB, g, dm, de;
};

struct Cn { float qa, qb, qc, wa, wb, ri, Cstep; };

__device__ __forceinline__ float shf(float v, int s) { return __shfl(v, s, 64); }
__device__ __forceinline__ float sx (float v, int m) { return __shfl_xor(v, m, 64); }

// Single-step potential: N(z'; F z, Qs) * prod_k N(y_k; b_k + z'_{h_k}, r)
__device__ __forceinline__ LP init_lane(float x0, float x1, const Cn& C, int i, int j) {
    LP P;
    float v = 0.0f;
    if (i == j) v = (i < 2) ? C.qa : C.qc;
    if ((i ^ j) == 2) v = C.wa;
    P.jFF = v;
    v = 0.0f;
    if (j == (i & 1))     v = (i < 2) ? -C.qa : -C.wa;
    if (j == (i & 1) + 2) v = (i < 2) ? -C.qb : -C.wb;
    P.jFL = v;
    P.jFB = 0.0f;
    v = 0.0f;
    if (i == j) v = ((i < 2) ? C.qa : C.qc) + (((i & 1) == 0) ? 2.0f*C.ri : 0.0f);
    if ((i ^ j) == 2) v = C.qb;
    P.jLL = v;
    P.jLB = (((i == 0) && (j < 2)) || ((i == 2) && (j >= 2))) ? C.ri : 0.0f;
    P.jBB = (i == j) ? C.ri : 0.0f;
    P.hF = 0.0f;
    P.hL = ((j & 1) == 0) ? C.ri * (x0 + x1) : 0.0f;
    P.hB = C.ri * ((j & 1) ? x1 : x0);
    P.g  = -C.ri * (x0*x0 + x1*x1) + C.Cstep;
    P.dm = 1.0f; P.de = 0.0f;
    return P;
}

// Compose P1 (earlier) o P2 (later), marginalizing the shared middle state.
// Adjugate-based 4x4 inverse (parallel, one reciprocal); 65 DS ops total.
__device__ __forceinline__ LP compose(const LP& P1, const LP& P2, int gb, int i, int j) {
    float hm = P1.hL + P2.hF;
    float Mb = P1.jLB + P2.jFB;
    float S  = P1.jLL + P2.jFF;
    float dm = P1.dm * P2.dm;
    float de = P1.de + P2.de;
    { int ex; dm = frexpf(dm, &ex); de += (float)ex; }
    // ----- adjugate inverse: lane (i,j) computes adj(i,j) = cof(j,i) -----
    const int r0 = (j == 0) ? 1 : 0;
    const int r1 = (j <= 1) ? 2 : 1;
    const int r2 = (j <= 2) ? 3 : 2;
    const int c0 = (i == 0) ? 1 : 0;
    const int c1 = (i <= 1) ? 2 : 1;
    const int c2 = (i <= 2) ? 3 : 2;
    float m00 = shf(S, gb + 4*r0 + c0), m01 = shf(S, gb + 4*r0 + c1), m02 = shf(S, gb + 4*r0 + c2);
    float m10 = shf(S, gb + 4*r1 + c0), m11 = shf(S, gb + 4*r1 + c1), m12 = shf(S, gb + 4*r1 + c2);
    float m20 = shf(S, gb + 4*r2 + c0), m21 = shf(S, gb + 4*r2 + c1), m22 = shf(S, gb + 4*r2 + c2);
    float d0 = fmaf(m11, m22, -m12*m21);
    float d1 = fmaf(m10, m22, -m12*m20);
    float d2 = fmaf(m10, m21, -m11*m20);
    float det3 = m00*d0 - m01*d1 + m02*d2;
    float adj = (((i + j) & 1) ? -det3 : det3);
    float sji = shf(S, gb + 4*j + i);
    float t = sji * adj;
    t += sx(t, 4); t += sx(t, 8);          // det, replicated
    float det = t;
    dm *= det; { int ex; dm = frexpf(dm, &ex); de += (float)ex; }
    const float Si = adj * (1.0f / det);
    // ----- hoisted broadcasts -----
    float sr[4], sc[4], f1r[4], f1T[4], f2c[4], f2T[4], mc[4], mT[4], hmc[4];
    #pragma unroll
    for (int r = 0; r < 4; ++r) {
        sr[r]  = shf(Si, gb + 4*i + r);
        sc[r]  = shf(Si, gb + 4*r + j);
        f1r[r] = shf(P1.jFL, gb + 4*i + r);
        f1T[r] = shf(P1.jFL, gb + 4*j + r);
        f2c[r] = shf(P2.jFL, gb + 4*r + j);
        f2T[r] = shf(P2.jFL, gb + 4*r + i);
        mc[r]  = shf(Mb, gb + 4*r + j);
        mT[r]  = shf(Mb, gb + 4*r + i);
        hmc[r] = shf(hm, gb + 5*r);
    }
    float A1 = 0.0f, C1 = 0.0f, B2 = 0.0f, v4i = 0.0f;
    #pragma unroll
    for (int r = 0; r < 4; ++r) {
        A1  = fmaf(f1r[r], sc[r], A1);
        C1  = fmaf(sr[r], mc[r], C1);
        B2  = fmaf(sr[r], f2c[r], B2);
        v4i = fmaf(sr[r], hmc[r], v4i);
    }
    float a1r[4], c1c[4], b2c[4], v4c[4];
    #pragma unroll
    for (int r = 0; r < 4; ++r) {
        a1r[r] = shf(A1, gb + 4*i + r);
        c1c[r] = shf(C1, gb + 4*r + j);
        b2c[r] = shf(B2, gb + 4*r + j);
        v4c[r] = shf(v4i, gb + 5*r);
    }
    float s_ff=0, s_fl=0, s_fb=0, s_ll=0, s_lb=0, s_bb=0, s_hf=0, s_hl=0, s_hb=0, s_g=0;
    #pragma unroll
    for (int r = 0; r < 4; ++r) {
        s_ff = fmaf(a1r[r], f1T[r], s_ff);
        s_fl = fmaf(a1r[r], f2c[r], s_fl);
        s_fb = fmaf(a1r[r], mc[r],  s_fb);
        s_ll = fmaf(f2T[r], b2c[r], s_ll);
        s_lb = fmaf(f2T[r], c1c[r], s_lb);
        s_bb = fmaf(mT[r],  c1c[r], s_bb);
        s_hf = fmaf(a1r[r], hmc[r], s_hf);
        s_hl = fmaf(f2c[r], v4c[r], s_hl);
        s_hb = fmaf(mc[r],  v4c[r], s_hb);
        s_g  = fmaf(hmc[r], v4c[r], s_g);
    }
    LP R;
    R.jFF = P1.jFF - s_ff;
    R.jFL = -s_fl;
    R.jFB = P1.jFB - s_fb;
    R.jLL = P2.jLL - s_ll;
    R.jLB = P2.jLB - s_lb;
    R.jBB = P1.jBB + P2.jBB - s_bb;
    R.hF  = P1.hF - shf(s_hf, gb + 5*j);
    R.hL  = P2.hL - s_hl;
    R.hB  = P1.hB + P2.hB - s_hb;
    R.g   = P1.g + P2.g + 2.0f*(float)L2PI + 0.5f*s_g;
    R.dm = dm; R.de = de;
    return R;
}

__device__ __forceinline__ LP fetchx(const LP& P, int m) {
    LP O;
    O.jFF = sx(P.jFF,m); O.jFL = sx(P.jFL,m); O.jFB = sx(P.jFB,m);
    O.jLL = sx(P.jLL,m); O.jLB = sx(P.jLB,m); O.jBB = sx(P.jBB,m);
    O.hF  = sx(P.hF,m);  O.hL  = sx(P.hL,m);  O.hB  = sx(P.hB,m);
    O.g   = sx(P.g,m);   O.dm  = sx(P.dm,m);  O.de  = sx(P.de,m);
    return O;
}
__device__ __forceinline__ LP csel(bool up, const LP& O, const LP& P) {
    LP A;
    A.jFF = up?O.jFF:P.jFF; A.jFL = up?O.jFL:P.jFL; A.jFB = up?O.jFB:P.jFB;
    A.jLL = up?O.jLL:P.jLL; A.jLB = up?O.jLB:P.jLB; A.jBB = up?O.jBB:P.jBB;
    A.hF  = up?O.hF :P.hF;  A.hL  = up?O.hL :P.hL;  A.hB  = up?O.hB :P.hB;
    A.g   = up?O.g  :P.g;   A.dm  = up?O.dm :P.dm;  A.de  = up?O.de :P.de;
    return A;
}
__device__ __forceinline__ void pot_store(float* p, const LP& P) {
    p[0]=P.jFF; p[1]=P.jFL; p[2]=P.jFB; p[3]=P.jLL; p[4]=P.jLB; p[5]=P.jBB;
    p[6]=P.hF;  p[7]=P.hL;  p[8]=P.hB;  p[9]=P.g;   p[10]=P.dm; p[11]=P.de;
}
__device__ __forceinline__ LP pot_load(const float* p) {
    LP P;
    P.jFF=p[0]; P.jFL=p[1]; P.jFB=p[2]; P.jLL=p[3]; P.jLB=p[4]; P.jBB=p[5];
    P.hF=p[6];  P.hL=p[7];  P.hB=p[8];  P.g=p[9];   P.dm=p[10]; P.de=p[11];
    return P;
}
__device__ __forceinline__ float cload(const float* p) {
    return __hip_atomic_load(p, __ATOMIC_RELAXED, __HIP_MEMORY_SCOPE_AGENT);
}
__device__ __forceinline__ LP pot_load_coh(const float* p) {
    LP P;
    P.jFF=cload(p+0); P.jFL=cload(p+1); P.jFB=cload(p+2);
    P.jLL=cload(p+3); P.jLB=cload(p+4); P.jBB=cload(p+5);
    P.hF=cload(p+6);  P.hL=cload(p+7);  P.hB=cload(p+8);
    P.g=cload(p+9);   P.dm=cload(p+10); P.de=cload(p+11);
    return P;
}

// ---------- Fused kernel: 32 blocks x 512 threads (8 waves).
// Produce: each block folds 64 steps (32 groups x 2; depth 1+2+3=6) -> ws+flag.
// Consume (block 0): spin, 32 groups load 1 pot each, depth 2+3=5, finalize,
// expand.  Total sequential composes: 11. ----------
__global__ __launch_bounds__(512)
void hmm_fused(const float* __restrict__ track,
               const float* __restrict__ bias_scales,
               const float* __restrict__ obs_noise_p,
               const float* __restrict__ trans_noise_p,
               float* __restrict__ ws,
               float* __restrict__ out)
{
    __shared__ float pool[2][8][16][13];
    __shared__ float sTi[8][8];
    __shared__ float sA[4];
    __shared__ float sLL;
    const int tid = (int)threadIdx.x;
    const int l = tid & 63, w = tid >> 6;
    const int i = (l >> 2) & 3, j = l & 3, gb = l & 48, g = (l >> 4) & 3;
    const int gid = w * 4 + g;            // group 0..31
    const int bid = (int)blockIdx.x;

    const double sg2d = (double)obs_noise_p[0] * (double)obs_noise_p[0];
    const double qn2d = (double)trans_noise_p[0] * (double)trans_noise_p[0];
    const double a00 = (double)bias_scales[0];
    const double a01 = (double)bias_scales[1];

    Cn C;
    C.qa = (float)(12.0/qn2d); C.qb = (float)(-6.0/qn2d); C.qc = (float)(4.0/qn2d);
    C.wa = (float)(6.0/qn2d);  C.wb = (float)(-2.0/qn2d);
    C.ri = (float)(32.0/sg2d);
    C.Cstep = (float)(-2.0*log(2.0*M_PI*sg2d/32.0) - 2.0*L2PI
                      - 0.5*(4.0*log(qn2d) - 2.0*log(12.0)));

    int* flags = (int*)(ws + 8192);       // after 32 KB; pots use 24 KB

    // ================= produce phase (all 32 blocks) =================
    {
        const int t0 = (bid * 32 + gid) * 2;
        LP P;
        #pragma unroll 1
        for (int op = 0; op < 6; ++op) {
            LP A, Bp;
            if (op == 0) {
                A  = init_lane(track[2*t0+0], track[2*t0+1], C, i, j);
                Bp = init_lane(track[2*t0+2], track[2*t0+3], C, i, j);
            } else if (op < 3) {
                const int m = 16 << (op - 1);
                LP O = fetchx(P, m);
                const bool up = (l & m) != 0;
                A  = csel(up, O, P);
                Bp = csel(up, P, O);
            } else {
                const int s = 1 << (op - 3);
                const int buf = (op - 3) & 1;
                if (l < 16) pot_store(&pool[buf][w][l][0], P);
                __syncthreads();
                LP O = pot_load(&pool[buf][w ^ s][l & 15][0]);
                const bool up = (w & s) != 0;
                A  = csel(up, O, P);
                Bp = csel(up, P, O);
            }
            P = compose(A, Bp, gb, i, j);
        }
        if (w == 0 && l < 16)
            pot_store(ws + ((size_t)bid * 16 + l) * 12, P);
        __threadfence();
        __syncthreads();
        if (tid == 0)
            __hip_atomic_store(&flags[bid * 32], MAGIC,
                               __ATOMIC_RELEASE, __HIP_MEMORY_SCOPE_AGENT);
    }
    if (bid != 0) return;

    // ================= consume phase (block 0) =================
    if (tid < 32) {
        while (__hip_atomic_load(&flags[tid * 32],
                                 __ATOMIC_ACQUIRE, __HIP_MEMORY_SCOPE_AGENT) != MAGIC)
            __builtin_amdgcn_s_sleep(2);
    }
    __syncthreads();
    __threadfence();

    LP P = pot_load_coh(ws + ((size_t)gid * 16 + (l & 15)) * 12);
    #pragma unroll 1
    for (int op = 0; op < 5; ++op) {
        LP A, Bp;
        if (op < 2) {
            const int m = 16 << op;
            LP O = fetchx(P, m);
            const bool up = (l & m) != 0;
            A  = csel(up, O, P);
            Bp = csel(up, P, O);
        } else {
            const int s = 1 << (op - 2);
            const int buf = (op - 2) & 1;
            if (l < 16) pot_store(&pool[buf][w][l][0], P);
            __syncthreads();
            LP O = pot_load(&pool[buf][w ^ s][l & 15][0]);
            const bool up = (w & s) != 0;
            A  = csel(up, O, P);
            Bp = csel(up, P, O);
        }
        P = compose(A, Bp, gb, i, j);
    }

    // ---------- final stage on wave 0 ----------
    if (w == 0) {
        const float a0i = (float)((i & 1) ? a01 : a00);
        P.jFF += (i == j) ? 1.0f : 0.0f;
        P.jBB += (i == j) ? 32.0f / a0i : 0.0f;
        P.g   += (float)(-4.0*L2PI + 2.0*log(32.0) - log(a00) - log(a01));
        float dm = P.dm, de = P.de;
        // marginalize z0: adjugate inverse of jFF
        float S = P.jFF;
        const int r0 = (j == 0) ? 1 : 0;
        const int r1 = (j <= 1) ? 2 : 1;
        const int r2 = (j <= 2) ? 3 : 2;
        const int c0 = (i == 0) ? 1 : 0;
        const int c1 = (i <= 1) ? 2 : 1;
        const int c2 = (i <= 2) ? 3 : 2;
        float m00 = shf(S, gb + 4*r0 + c0), m01 = shf(S, gb + 4*r0 + c1), m02 = shf(S, gb + 4*r0 + c2);
        float m10 = shf(S, gb + 4*r1 + c0), m11 = shf(S, gb + 4*r1 + c1), m12 = shf(S, gb + 4*r1 + c2);
        float m20 = shf(S, gb + 4*r2 + c0), m21 = shf(S, gb + 4*r2 + c1), m22 = shf(S, gb + 4*r2 + c2);
        float d0 = fmaf(m11, m22, -m12*m21);
        float d1 = fmaf(m10, m22, -m12*m20);
        float d2 = fmaf(m10, m21, -m11*m20);
        float det3 = m00*d0 - m01*d1 + m02*d2;
        float adj = (((i + j) & 1) ? -det3 : det3);
        float sji = shf(S, gb + 4*j + i);
        float tdet = sji * adj;
        tdet += sx(tdet, 4); tdet += sx(tdet, 8);
        float det = tdet;
        dm *= det; { int ex; dm = frexpf(dm, &ex); de += (float)ex; }
        const float Si = adj * (1.0f / det);
        float sr[4], fr[4], fT[4], bc[4], bT[4], hfc[4];
        #pragma unroll
        for (int r = 0; r < 4; ++r) {
            sr[r]  = shf(Si, gb + 4*i + r);
            fr[r]  = shf(P.jFL, gb + 4*r + i);
            fT[r]  = shf(P.jFL, gb + 4*r + j);
            bc[r]  = shf(P.jFB, gb + 4*r + i);
            bT[r]  = shf(P.jFB, gb + 4*r + j);
            hfc[r] = shf(P.hF, gb + 5*r);
        }
        float YL = 0.0f, YB = 0.0f, yFi = 0.0f;
        #pragma unroll
        for (int r = 0; r < 4; ++r) {
            YL  = fmaf(sr[r], fT[r], YL);
            YB  = fmaf(sr[r], bT[r], YB);
            yFi = fmaf(sr[r], hfc[r], yFi);
        }
        float ylc[4], ybc[4], yfc[4];
        #pragma unroll
        for (int r = 0; r < 4; ++r) {
            ylc[r] = shf(YL, gb + 4*r + j);
            ybc[r] = shf(YB, gb + 4*r + j);
            yfc[r] = shf(yFi, gb + 5*r);
        }
        float s1 = 0.0f, s2 = 0.0f, s3 = 0.0f, sh1 = 0.0f, sh2 = 0.0f, qF = 0.0f;
        #pragma unroll
        for (int r = 0; r < 4; ++r) {
            s1  = fmaf(fr[r], ylc[r], s1);
            s2  = fmaf(fr[r], ybc[r], s2);
            s3  = fmaf(bc[r], ybc[r], s3);
            sh1 = fmaf(fT[r], yfc[r], sh1);
            sh2 = fmaf(bT[r], yfc[r], sh2);
            qF  = fmaf(hfc[r], yfc[r], qF);
        }
        float J8ss = P.jLL - s1;
        float J8sb = P.jLB - s2;
        float J8bb = P.jBB - s3;
        float h8s  = P.hL - sh1;
        float h8b  = P.hB - sh2;
        float g8   = P.g + 2.0f*(float)L2PI + 0.5f*qF;

        // 8x8 stage across all 64 lanes: lane = (I,J)
        const int I = l >> 3, J = l & 7, i4 = I & 3, j4 = J & 3;
        float ss  = shf(J8ss, 4*i4 + j4);
        float sb  = shf(J8sb, 4*i4 + j4);
        float sbT = shf(J8sb, 4*j4 + i4);
        float bb  = shf(J8bb, 4*i4 + j4);
        float A8 = (I < 4) ? ((J < 4) ? ss : sb) : ((J < 4) ? sbT : bb);
        const float J8sav = A8;
        float h8v = (J < 4) ? shf(h8s, j4) : shf(h8b, j4);
        float h8r = (I < 4) ? shf(h8s, i4) : shf(h8b, i4);
        float K8 = (I == J) ? 1.0f : 0.0f;
        #pragma unroll 1
        for (int p = 0; p < 8; ++p) {
            float piv = shf(A8, 9*p);
            dm *= piv; { int ex; dm = frexpf(dm, &ex); de += (float)ex; }
            float ip = 1.0f / piv;
            float Ap = shf(A8, 8*p + J) * ip;
            float Kp = shf(K8, 8*p + J) * ip;
            float f  = shf(A8, 8*I + p);
            bool isp = (I == p);
            A8 = isp ? A8 * ip : fmaf(-f, Ap, A8);
            K8 = isp ? K8 * ip : fmaf(-f, Kp, K8);
        }
        float tq = h8r * K8 * h8v;
        tq += sx(tq,1); tq += sx(tq,2); tq += sx(tq,4);
        tq += sx(tq,8); tq += sx(tq,16); tq += sx(tq,32);

        double ll = (double)g8 + 4.0*L2PI
                    - 0.5*(log((double)dm) + (double)de*LN2) + 0.5*(double)tq;
        const double Td = 2048.0;
        const double c0d = sg2d/a00, c1d = sg2d/a01;
        ll += -31.0*(Td*(L2PI + log(sg2d)) + log((c0d+Td)/c0d))
              -31.0*(Td*(L2PI + log(sg2d)) + log((c1d+Td)/c1d))
              -2.0*Td*log(32.0);

        const float i32 = 1.0f/32.0f, irn = 0.176776695296637f;
        int a = (I >= 4) ? I - 4 : I + 4;
        int b = (J >= 4) ? J - 4 : J + 4;
        float scale = (I >= 4 && J >= 4) ? i32 : (((I >= 4) != (J >= 4)) ? irn : 1.0f);
        sTi[a][b] = J8sav * scale;
        if (l < 4) {
            double a0k = (l & 1) ? a01 : a00;
            sA[l] = (float)(a0k*sg2d/(sg2d + Td*a0k));
        }
        if (l == 0) sLL = (float)ll;
    }
    __syncthreads();

    // ---------- expand 1 + 132x132 outputs ----------
    const float inv32 = 1.0f/32.0f;
    const float invrn = 0.176776695296637f;
    const int total = 1 + 132*132;
    #pragma unroll 1
    for (int idx = tid; idx < total; idx += 512) {
        float v;
        if (idx == 0) {
            v = sLL;
        } else {
            int el = idx - 1;
            int r = el / 132;
            int cc = el - 132*r;
            if (r < 128) {
                int ki = ((r >> 6) << 1) | (r & 1);
                if (cc < 128) {
                    int kj = ((cc >> 6) << 1) | (cc & 1);
                    v = sTi[ki][kj] * inv32;
                    if (ki == kj) {
                        float ia = 1.0f / sA[ki];
                        v -= ia * inv32;
                        if (r == cc) v += ia;
                    }
                } else {
                    v = sTi[ki][cc - 124] * invrn;
                }
            } else {
                if (cc < 128) {
                    int kj = ((cc >> 6) << 1) | (cc & 1);
                    v = sTi[kj][r - 124] * invrn;
                } else {
                    v = sTi[r - 124][cc - 124];
                }
            }
        }
        out[idx] = v;
    }
}

extern "C" void kernel_launch(void* const* d_in, const int* in_sizes, int n_in,
                              void* d_out, int out_size, void* d_ws, size_t ws_size,
                              hipStream_t stream) {
    (void)in_sizes; (void)n_in; (void)out_size; (void)ws_size;
    const float* track       = (const float*)d_in[0];
    const float* bias_scales = (const float*)d_in[1];
    const float* obs_noise   = (const float*)d_in[2];
    const float* trans_noise = (const float*)d_in[3];
    float* out = (float*)d_out;
    float* ws  = (float*)d_ws;   // 24 KB pots + flags at +32 KB (0xAA poison != MAGIC)
    hipLaunchKernelGGL(hmm_fused, dim3(32), dim3(512), 0, stream,
                       track, bias_scales, obs_noise, trans_noise, ws, out);
}